// Round 7
// baseline (146.288 us; speedup 1.0000x reference)
//
#include <hip/hip_runtime.h>

typedef _Float16 f16;
typedef unsigned short u16;
typedef __attribute__((ext_vector_type(8))) f16 f16x8;
typedef __attribute__((ext_vector_type(4))) f16 f16x4;
typedef __attribute__((ext_vector_type(4))) float floatx4;

#define NPIX 4096
#define KT   128          // keys per attention tile
#define NT   (NPIX / KT)  // 32 key tiles
#define VROW 136          // padded V LDS row (128 keys + 8) in f16

// ---------------------------------------------------------------------------
// Kernel 1: QKV projection as fp16 MFMA GEMM.  (round-0 form, known-good)
// grid (64 p-tiles, 6 o-tiles of 64, 4 b), block 256 (4 waves).
// ---------------------------------------------------------------------------
__global__ __launch_bounds__(256) void qkv_mfma(
    const float* __restrict__ x, const float* __restrict__ w,
    f16* __restrict__ qh, f16* __restrict__ kh, f16* __restrict__ vth)
{
    __shared__ f16 wlds[64 * 136];     // [o][c] padded (+8) -> conflict-free frags
    const int tid  = threadIdx.x;
    const int wave = tid >> 6;
    const int lane = tid & 63;
    const int quad = lane >> 4;
    const int l16  = lane & 15;
    const int pbase = blockIdx.x * 64;
    const int y     = blockIdx.y;      // o-tile of 64; type = y>>1
    const int b     = blockIdx.z;

#pragma unroll
    for (int i = 0; i < 8; ++i) {
        int idx = i * 256 + tid;               // 2048 float4
        int o = idx >> 5, ch = idx & 31;
        float4 wv = *(const float4*)(w + (size_t)(y * 64 + o) * 128 + ch * 4);
        f16x4 h; h[0] = (f16)wv.x; h[1] = (f16)wv.y; h[2] = (f16)wv.z; h[3] = (f16)wv.w;
        *(f16x4*)&wlds[o * 136 + ch * 4] = h;
    }
    __syncthreads();

    const float* xb = x + (size_t)b * 128 * NPIX;
    const int type = y >> 1;                   // 0=q 1=k 2=v

    if (type < 2) {
        // ---- C[p][o]: A = X^T (global), B = W (LDS) ----
        const int p_row = pbase + wave * 16 + l16;
        f16x8 af[4];
#pragma unroll
        for (int kc = 0; kc < 4; ++kc) {
            const int c0 = kc * 32 + quad * 8;
#pragma unroll
            for (int j = 0; j < 8; ++j)
                af[kc][j] = (f16)xb[(size_t)(c0 + j) * NPIX + p_row];
        }
        floatx4 acc[4];
#pragma unroll
        for (int n = 0; n < 4; ++n) acc[n] = floatx4{0.f, 0.f, 0.f, 0.f};
#pragma unroll
        for (int n = 0; n < 4; ++n)
#pragma unroll
            for (int kc = 0; kc < 4; ++kc) {
                f16x8 bf = *(const f16x8*)&wlds[(n * 16 + l16) * 136 + kc * 32 + quad * 8];
                acc[n] = __builtin_amdgcn_mfma_f32_16x16x32_f16(af[kc], bf, acc[n], 0, 0, 0);
            }
        const float qs = (type == 0) ? 0.17677669529663687f * 1.4426950408889634f : 1.0f;
        f16* dst = (type == 0) ? qh : kh;
#pragma unroll
        for (int n = 0; n < 4; ++n) {
            const int og   = y * 64 + n * 16 + l16;
            const int head = (og >> 5) & 3;
            const int d    = og & 31;
            f16* base = dst + (size_t)(b * 4 + head) * NPIX * 32;
#pragma unroll
            for (int r = 0; r < 4; ++r) {
                const int p = pbase + wave * 16 + quad * 4 + r;
                base[(size_t)p * 32 + d] = (f16)(acc[n][r] * qs);
            }
        }
    } else {
        // ---- C[o][p]: A = W (LDS), B = X (global) ----
        const int p_col = pbase + wave * 16 + l16;
        f16x8 bf[4];
#pragma unroll
        for (int kc = 0; kc < 4; ++kc) {
            const int c0 = kc * 32 + quad * 8;
#pragma unroll
            for (int j = 0; j < 8; ++j)
                bf[kc][j] = (f16)xb[(size_t)(c0 + j) * NPIX + p_col];
        }
        floatx4 acc[4];
#pragma unroll
        for (int m = 0; m < 4; ++m) acc[m] = floatx4{0.f, 0.f, 0.f, 0.f};
#pragma unroll
        for (int m = 0; m < 4; ++m)
#pragma unroll
            for (int kc = 0; kc < 4; ++kc) {
                f16x8 af = *(const f16x8*)&wlds[(m * 16 + l16) * 136 + kc * 32 + quad * 8];
                acc[m] = __builtin_amdgcn_mfma_f32_16x16x32_f16(af, bf[kc], acc[m], 0, 0, 0);
            }
#pragma unroll
        for (int m = 0; m < 4; ++m)
#pragma unroll
            for (int r = 0; r < 4; ++r) {
                const int og   = y * 64 + m * 16 + quad * 4 + r;
                const int head = (og >> 5) & 3;
                const int d    = og & 31;
                vth[((size_t)(b * 4 + head) * 32 + d) * NPIX + p_col] = (f16)acc[m][r];
            }
    }
}

// ---------------------------------------------------------------------------
// Kernel 2: flash attention — v7: 16 q per wave, 4 independent waves/SIMD.
// Ledger: baseline(63.8) == v5(63.2); all deviations regressed. v4/v6 proved
// V must be block-shared via LDS; v5 proved direct-global K is benign; the
// residual is overlap starvation at 2 independent waves/SIMD. Fix: halve the
// wave's q-tile (16 q, h-loop gone) -> grid (64,16) = 1024 blocks = 4
// blocks/CU = 4 INDEPENDENT waves/SIMD (one per unsynced co-resident block).
// No cross-wave combine (v3's sin #1); single V staging per block (sin #2);
// HBM flat. Per-wave state halves -> fits 128 VGPR (enforced: bounds(256,4)).
// ---------------------------------------------------------------------------
__global__ __launch_bounds__(256, 4) void attn_kernel(
    const f16* __restrict__ qh, const f16* __restrict__ kh,
    const f16* __restrict__ vth, f16* __restrict__ att)
{
    __shared__ f16 vlds[2][32 * VROW];   // 2 x 8.5 KB, padded [d][key]

    const int tid  = threadIdx.x;
    const int wave = tid >> 6;
    const int lane = tid & 63;
    const int quad = lane >> 4;
    const int l16  = lane & 15;
    const int bh   = blockIdx.y;
    const int qbase = blockIdx.x * 64 + wave * 16;

    const f16* kb = kh + (size_t)bh * NPIX * 32;
    const f16* vb = vth + (size_t)bh * 32 * NPIX;
    // per-lane K fragment pointer: row l16 (+t*16), col quad*8 within a tile
    const f16* kp = kb + (size_t)l16 * 32 + quad * 8;

    // V staging geometry: 32 d-rows x 128 keys = 512 int4, 2/thread
    const int vr = tid >> 3, vcc = (tid & 7) * 2;
    const int voff = vr * VROW + vcc * 8;
    const f16* vrow = vb + (size_t)vr * NPIX;

    // Q B-frag (B[k=d][n=q]): one 16-q subtile per wave
    const f16x8 qB = *(const f16x8*)(qh + ((size_t)bh * NPIX + qbase + l16) * 32 + quad * 8);

    floatx4 oacc[2];
    oacc[0] = floatx4{0.f, 0.f, 0.f, 0.f};
    oacc[1] = floatx4{0.f, 0.f, 0.f, 0.f};
    float lsum = 0.f;

    // prologue: V tile 0 -> vlds[0]
    {
        const int4* vs = (const int4*)vrow;
        int4 a = vs[vcc], b2 = vs[vcc + 1];
        *(int4*)&vlds[0][voff]     = a;
        *(int4*)&vlds[0][voff + 8] = b2;
    }
    __syncthreads();

    for (int kt = 0; kt < NT; ++kt) {
        const int cur = kt & 1;
        const bool more = (kt + 1 < NT);

        // T14: issue next V tile's global loads first; publish after compute
        int4 nv0, nv1;
        if (more) {
            const int4* vs = (const int4*)(vrow + (size_t)(kt + 1) * KT);
            nv0 = vs[vcc]; nv1 = vs[vcc + 1];
        }

        // K A-frags for the CURRENT tile direct from global (L1/L2-served;
        // latency filled by the other 3 independent waves on this SIMD)
        f16x8 kf[8];
#pragma unroll
        for (int t = 0; t < 8; ++t)
            kf[t] = *(const f16x8*)(kp + (size_t)(kt * KT + t * 16) * 32);

        // V B-frags from LDS
        f16x4 vf[8][2];
#pragma unroll
        for (int c = 0; c < 8; ++c)
#pragma unroll
            for (int dh = 0; dh < 2; ++dh)
                vf[c][dh] = *(const f16x4*)&vlds[cur][(dh * 16 + l16) * VROW + c * 16 + quad * 4];

        // S^T: D[key][q], 8 subtiles of 16 keys, full K=32 reduction
        floatx4 st[8];
#pragma unroll
        for (int t = 0; t < 8; ++t) {
            floatx4 z = {0.f, 0.f, 0.f, 0.f};
            st[t] = __builtin_amdgcn_mfma_f32_16x16x32_f16(kf[t], qB, z, 0, 0, 0);
        }
        // exp2 in-lane -> P A-frags (P[q=l16][key=quad*4+r]); f32 row sums
        f16x4 pf[8];
        float ls = 0.f;
#pragma unroll
        for (int c = 0; c < 8; ++c)
#pragma unroll
            for (int r = 0; r < 4; ++r) {
                float e = __builtin_amdgcn_exp2f(st[c][r]);
                ls += e;
                pf[c][r] = (f16)e;
            }
        lsum += ls;
        // PV: O[q][d] += P[q][key] * V[key][d], K=16 chunks
#pragma unroll
        for (int c = 0; c < 8; ++c) {
            oacc[0] = __builtin_amdgcn_mfma_f32_16x16x16f16(pf[c], vf[c][0], oacc[0], 0, 0, 0);
            oacc[1] = __builtin_amdgcn_mfma_f32_16x16x16f16(pf[c], vf[c][1], oacc[1], 0, 0, 0);
        }

        // publish next V tile into the other buffer
        if (more) {
            *(int4*)&vlds[cur ^ 1][voff]     = nv0;
            *(int4*)&vlds[cur ^ 1][voff + 8] = nv1;
        }
        __syncthreads();
    }

    // epilogue: reduce lsum across quads (q lives in l16), divide, store f16
    {
        float l = lsum;
        l += __shfl_xor(l, 16);
        l += __shfl_xor(l, 32);
        const float inv = 1.0f / l;            // valid per q = l16
#pragma unroll
        for (int r = 0; r < 4; ++r) {
            const float invr = __shfl(inv, quad * 4 + r);   // inv for q-row quad*4+r
            const int q = qbase + quad * 4 + r;
            f16* ob = att + ((size_t)bh * NPIX + q) * 32;
            ob[l16]      = (f16)(oacc[0][r] * invr);
            ob[16 + l16] = (f16)(oacc[1][r] * invr);
        }
    }
}

// ---------------------------------------------------------------------------
// Kernel 3: output projection as fp16 MFMA GEMM.  (round-0 form, known-good)
// C[o][p] = Wp[o][c] * att^T[c][p] + bias; att[bh][p][32] IS the natural
// B-fragment layout (16B contiguous per lane). Stores coalesced fp32.
// grid (64 p-tiles, 4 b), block 256 (4 waves).
// ---------------------------------------------------------------------------
__global__ __launch_bounds__(256) void proj_mfma(
    const f16* __restrict__ att, const float* __restrict__ wp,
    const float* __restrict__ bp, float* __restrict__ out)
{
    __shared__ f16 wplds[128 * 136];   // [o][c] padded, 34.8 KB
    __shared__ float bplds[128];
    const int tid  = threadIdx.x;
    const int wave = tid >> 6;
    const int lane = tid & 63;
    const int quad = lane >> 4;
    const int l16  = lane & 15;
    const int pbase = blockIdx.x * 64;
    const int b     = blockIdx.y;

    if (tid < 128) bplds[tid] = bp[tid];
#pragma unroll
    for (int i = 0; i < 16; ++i) {
        int idx = i * 256 + tid;               // 4096 float4 = 128*128 floats
        int o = idx >> 5, ch = idx & 31;
        float4 wv = *(const float4*)(wp + (size_t)o * 128 + ch * 4);
        f16x4 h; h[0] = (f16)wv.x; h[1] = (f16)wv.y; h[2] = (f16)wv.z; h[3] = (f16)wv.w;
        *(f16x4*)&wplds[o * 136 + ch * 4] = h;
    }
    __syncthreads();

    const f16* ab = att + (size_t)b * 4 * NPIX * 32;
    const int p_col = pbase + wave * 16 + l16;
    f16x8 bf[4];
#pragma unroll
    for (int kc = 0; kc < 4; ++kc)
        bf[kc] = *(const f16x8*)(ab + ((size_t)kc * NPIX + p_col) * 32 + quad * 8);

    floatx4 acc[8];
#pragma unroll
    for (int m = 0; m < 8; ++m) acc[m] = floatx4{0.f, 0.f, 0.f, 0.f};
#pragma unroll
    for (int m = 0; m < 8; ++m)
#pragma unroll
        for (int kc = 0; kc < 4; ++kc) {
            f16x8 af = *(const f16x8*)&wplds[(m * 16 + l16) * 136 + kc * 32 + quad * 8];
            acc[m] = __builtin_amdgcn_mfma_f32_16x16x32_f16(af, bf[kc], acc[m], 0, 0, 0);
        }

#pragma unroll
    for (int m = 0; m < 8; ++m)
#pragma unroll
        for (int r = 0; r < 4; ++r) {
            const int o = m * 16 + quad * 4 + r;
            out[((size_t)b * 128 + o) * NPIX + p_col] = acc[m][r] + bplds[o];
        }
}

// ---------------------------------------------------------------------------
extern "C" void kernel_launch(void* const* d_in, const int* in_sizes, int n_in,
                              void* d_out, int out_size, void* d_ws, size_t ws_size,
                              hipStream_t stream)
{
    const float* x      = (const float*)d_in[0];
    const float* w_qkv  = (const float*)d_in[1];
    const float* w_proj = (const float*)d_in[2];
    const float* b_proj = (const float*)d_in[3];
    float* out = (float*)d_out;

    char* ws = (char*)d_ws;
    f16* qh  = (f16*)(ws);                // 4 MB [bh][p][32], pre-scaled
    f16* kh  = (f16*)(ws + (4u << 20));   // 4 MB [bh][p][32]
    f16* vth = (f16*)(ws + (8u << 20));   // 4 MB [bh][d][p]
    f16* att = (f16*)(ws + (12u << 20));  // 4 MB [bh][p][32]

    qkv_mfma<<<dim3(64, 6, 4), 256, 0, stream>>>(x, w_qkv, qh, kh, vth);
    attn_kernel<<<dim3(64, 16, 1), 256, 0, stream>>>(qh, kh, vth, att);
    proj_mfma<<<dim3(64, 4, 1), 256, 0, stream>>>(att, w_proj, b_proj, out);
}

// Round 8
// 125.534 us; speedup vs baseline: 1.1653x; 1.1653x over previous
//
#include <hip/hip_runtime.h>

typedef _Float16 f16;
typedef unsigned short u16;
typedef __attribute__((ext_vector_type(8))) f16 f16x8;
typedef __attribute__((ext_vector_type(4))) f16 f16x4;
typedef __attribute__((ext_vector_type(4))) float floatx4;
typedef __attribute__((ext_vector_type(2))) __fp16 h2;   // builtin half type

union pk4 { h2 h[2]; f16x4 v; };   // cvt_pkrtz pairs <-> MFMA A-frag

#define NPIX 4096
#define KT   128          // keys per attention tile
#define NT   (NPIX / KT)  // 32 key tiles
#define VROW 136          // padded V LDS row (128 keys + 8) in f16

// ---------------------------------------------------------------------------
// Kernel 1: QKV projection as fp16 MFMA GEMM.  (round-0 form, known-good)
// grid (64 p-tiles, 6 o-tiles of 64, 4 b), block 256 (4 waves).
// ---------------------------------------------------------------------------
__global__ __launch_bounds__(256) void qkv_mfma(
    const float* __restrict__ x, const float* __restrict__ w,
    f16* __restrict__ qh, f16* __restrict__ kh, f16* __restrict__ vth)
{
    __shared__ f16 wlds[64 * 136];     // [o][c] padded (+8) -> conflict-free frags
    const int tid  = threadIdx.x;
    const int wave = tid >> 6;
    const int lane = tid & 63;
    const int quad = lane >> 4;
    const int l16  = lane & 15;
    const int pbase = blockIdx.x * 64;
    const int y     = blockIdx.y;      // o-tile of 64; type = y>>1
    const int b     = blockIdx.z;

#pragma unroll
    for (int i = 0; i < 8; ++i) {
        int idx = i * 256 + tid;               // 2048 float4
        int o = idx >> 5, ch = idx & 31;
        float4 wv = *(const float4*)(w + (size_t)(y * 64 + o) * 128 + ch * 4);
        f16x4 h; h[0] = (f16)wv.x; h[1] = (f16)wv.y; h[2] = (f16)wv.z; h[3] = (f16)wv.w;
        *(f16x4*)&wlds[o * 136 + ch * 4] = h;
    }
    __syncthreads();

    const float* xb = x + (size_t)b * 128 * NPIX;
    const int type = y >> 1;                   // 0=q 1=k 2=v

    if (type < 2) {
        // ---- C[p][o]: A = X^T (global), B = W (LDS) ----
        const int p_row = pbase + wave * 16 + l16;
        f16x8 af[4];
#pragma unroll
        for (int kc = 0; kc < 4; ++kc) {
            const int c0 = kc * 32 + quad * 8;
#pragma unroll
            for (int j = 0; j < 8; ++j)
                af[kc][j] = (f16)xb[(size_t)(c0 + j) * NPIX + p_row];
        }
        floatx4 acc[4];
#pragma unroll
        for (int n = 0; n < 4; ++n) acc[n] = floatx4{0.f, 0.f, 0.f, 0.f};
#pragma unroll
        for (int n = 0; n < 4; ++n)
#pragma unroll
            for (int kc = 0; kc < 4; ++kc) {
                f16x8 bf = *(const f16x8*)&wlds[(n * 16 + l16) * 136 + kc * 32 + quad * 8];
                acc[n] = __builtin_amdgcn_mfma_f32_16x16x32_f16(af[kc], bf, acc[n], 0, 0, 0);
            }
        const float qs = (type == 0) ? 0.17677669529663687f * 1.4426950408889634f : 1.0f;
        f16* dst = (type == 0) ? qh : kh;
#pragma unroll
        for (int n = 0; n < 4; ++n) {
            const int og   = y * 64 + n * 16 + l16;
            const int head = (og >> 5) & 3;
            const int d    = og & 31;
            f16* base = dst + (size_t)(b * 4 + head) * NPIX * 32;
#pragma unroll
            for (int r = 0; r < 4; ++r) {
                const int p = pbase + wave * 16 + quad * 4 + r;
                base[(size_t)p * 32 + d] = (f16)(acc[n][r] * qs);
            }
        }
    } else {
        // ---- C[o][p]: A = W (LDS), B = X (global) ----
        const int p_col = pbase + wave * 16 + l16;
        f16x8 bf[4];
#pragma unroll
        for (int kc = 0; kc < 4; ++kc) {
            const int c0 = kc * 32 + quad * 8;
#pragma unroll
            for (int j = 0; j < 8; ++j)
                bf[kc][j] = (f16)xb[(size_t)(c0 + j) * NPIX + p_col];
        }
        floatx4 acc[4];
#pragma unroll
        for (int m = 0; m < 4; ++m) acc[m] = floatx4{0.f, 0.f, 0.f, 0.f};
#pragma unroll
        for (int m = 0; m < 4; ++m)
#pragma unroll
            for (int kc = 0; kc < 4; ++kc) {
                f16x8 af = *(const f16x8*)&wlds[(m * 16 + l16) * 136 + kc * 32 + quad * 8];
                acc[m] = __builtin_amdgcn_mfma_f32_16x16x32_f16(af, bf[kc], acc[m], 0, 0, 0);
            }
#pragma unroll
        for (int m = 0; m < 4; ++m)
#pragma unroll
            for (int r = 0; r < 4; ++r) {
                const int og   = y * 64 + m * 16 + quad * 4 + r;
                const int head = (og >> 5) & 3;
                const int d    = og & 31;
                vth[((size_t)(b * 4 + head) * 32 + d) * NPIX + p_col] = (f16)acc[m][r];
            }
    }
}

// ---------------------------------------------------------------------------
// Kernel 2: flash attention — v8 = v5 (known-good 63.2us) + VALU cut only.
//  - v_cvt_pkrtz_f16_f32 packs 2 f32->f16 per op (was 2 cvt + pack).
//  - v_fdot2_f32_f16 with (1,1) accumulates lsum from the PACKED f16 P pairs:
//    32 dot ops replace 64 f32 adds, f32-precise, zero MFMA-pipe cost, and
//    the denominator now sums the exact f16 values used in the numerator
//    (quantization cancels in the ratio).
// Structure identical to v5: K direct-from-global w/ register ping-pong,
// V double-buffered LDS w/ T14 split, 1 barrier/kt, QK(h0,h1) then
// exp(h0), PV(h0)||exp(h1), PV(h1).
// grid (32 q-blocks of 128, 16 bh), block 256 (4 waves x 32 q).
// ---------------------------------------------------------------------------
#define ATTN_STEP(BUF, KF, KFN, TNXT)                                          \
{                                                                              \
    /* prefetch next K tile's fragments (consumed next step) */                \
    if ((TNXT) < NT) {                                                         \
        _Pragma("unroll")                                                      \
        for (int t = 0; t < 8; ++t)                                            \
            KFN[t] = *(const f16x8*)(kp + (size_t)((TNXT) * KT + t * 16) * 32);\
    }                                                                          \
    /* T14: issue next V tile's global loads now, publish after compute */     \
    int4 nv0, nv1;                                                             \
    if ((TNXT) < NT) {                                                         \
        const int4* vs = (const int4*)(vrow + (TNXT) * KT);                    \
        nv0 = vs[vcc]; nv1 = vs[vcc + 1];                                      \
    }                                                                          \
    /* V frags for current tile from LDS */                                    \
    f16x4 vf[8][2];                                                            \
    _Pragma("unroll")                                                          \
    for (int c = 0; c < 8; ++c) {                                              \
        _Pragma("unroll")                                                      \
        for (int dh = 0; dh < 2; ++dh)                                         \
            vf[c][dh] = *(const f16x4*)&vlds[BUF][(dh * 16 + l16) * VROW + c * 16 + quad * 4]; \
    }                                                                          \
    /* S^T for BOTH q-subtiles first (16 MFMA back-to-back) */                 \
    floatx4 st0[8], st1[8];                                                    \
    _Pragma("unroll")                                                          \
    for (int t = 0; t < 8; ++t) {                                              \
        floatx4 z = {0.f, 0.f, 0.f, 0.f};                                      \
        st0[t] = __builtin_amdgcn_mfma_f32_16x16x32_f16(KF[t], qB[0], z, 0, 0, 0); \
    }                                                                          \
    _Pragma("unroll")                                                          \
    for (int t = 0; t < 8; ++t) {                                              \
        floatx4 z = {0.f, 0.f, 0.f, 0.f};                                      \
        st1[t] = __builtin_amdgcn_mfma_f32_16x16x32_f16(KF[t], qB[1], z, 0, 0, 0); \
    }                                                                          \
    /* exp(h0): pkrtz-pack + fdot2 row sums (overlaps tail of QK(h1)) */       \
    f16x4 pf0[8], pf1[8];                                                      \
    float ls0 = 0.f, ls1 = 0.f;                                                \
    _Pragma("unroll")                                                          \
    for (int c = 0; c < 8; ++c) {                                              \
        float e0 = __builtin_amdgcn_exp2f(st0[c][0]);                          \
        float e1 = __builtin_amdgcn_exp2f(st0[c][1]);                          \
        float e2 = __builtin_amdgcn_exp2f(st0[c][2]);                          \
        float e3 = __builtin_amdgcn_exp2f(st0[c][3]);                          \
        pk4 u;                                                                 \
        u.h[0] = __builtin_amdgcn_cvt_pkrtz(e0, e1);                           \
        u.h[1] = __builtin_amdgcn_cvt_pkrtz(e2, e3);                           \
        pf0[c] = u.v;                                                          \
        ls0 = __builtin_amdgcn_fdot2(u.h[0], one2, ls0, false);                \
        ls0 = __builtin_amdgcn_fdot2(u.h[1], one2, ls0, false);                \
    }                                                                          \
    /* PV(h0) MFMAs interleaved with exp(h1) VALU: both pipes busy */          \
    _Pragma("unroll")                                                          \
    for (int c = 0; c < 8; ++c) {                                              \
        oacc[0][0] = __builtin_amdgcn_mfma_f32_16x16x16f16(pf0[c], vf[c][0], oacc[0][0], 0, 0, 0); \
        oacc[0][1] = __builtin_amdgcn_mfma_f32_16x16x16f16(pf0[c], vf[c][1], oacc[0][1], 0, 0, 0); \
        float e0 = __builtin_amdgcn_exp2f(st1[c][0]);                          \
        float e1 = __builtin_amdgcn_exp2f(st1[c][1]);                          \
        float e2 = __builtin_amdgcn_exp2f(st1[c][2]);                          \
        float e3 = __builtin_amdgcn_exp2f(st1[c][3]);                          \
        pk4 u;                                                                 \
        u.h[0] = __builtin_amdgcn_cvt_pkrtz(e0, e1);                           \
        u.h[1] = __builtin_amdgcn_cvt_pkrtz(e2, e3);                           \
        pf1[c] = u.v;                                                          \
        ls1 = __builtin_amdgcn_fdot2(u.h[0], one2, ls1, false);                \
        ls1 = __builtin_amdgcn_fdot2(u.h[1], one2, ls1, false);                \
    }                                                                          \
    lsum[0] += ls0; lsum[1] += ls1;                                            \
    _Pragma("unroll")                                                          \
    for (int c = 0; c < 8; ++c) {                                              \
        oacc[1][0] = __builtin_amdgcn_mfma_f32_16x16x16f16(pf1[c], vf[c][0], oacc[1][0], 0, 0, 0); \
        oacc[1][1] = __builtin_amdgcn_mfma_f32_16x16x16f16(pf1[c], vf[c][1], oacc[1][1], 0, 0, 0); \
    }                                                                          \
    /* publish next V tile into the other buffer (consumed last step) */       \
    if ((TNXT) < NT) {                                                         \
        *(int4*)&vlds[(BUF) ^ 1][voff]     = nv0;                              \
        *(int4*)&vlds[(BUF) ^ 1][voff + 8] = nv1;                              \
    }                                                                          \
    __syncthreads();                                                           \
}

__global__ __launch_bounds__(256, 2) void attn_kernel(
    const f16* __restrict__ qh, const f16* __restrict__ kh,
    const f16* __restrict__ vth, f16* __restrict__ att)
{
    __shared__ f16 vlds[2][32 * VROW];   // 2 x 8.5 KB, padded [d][key]

    const int tid  = threadIdx.x;
    const int wave = tid >> 6;
    const int lane = tid & 63;
    const int quad = lane >> 4;
    const int l16  = lane & 15;
    const int bh   = blockIdx.y;
    const int qbase = blockIdx.x * 128 + wave * 32;

    const f16* kb = kh + (size_t)bh * NPIX * 32;
    const f16* vb = vth + (size_t)bh * 32 * NPIX;
    // per-lane K fragment pointer: row l16 (+t*16), col quad*8 within a tile
    const f16* kp = kb + (size_t)l16 * 32 + quad * 8;

    // V staging geometry: 32 d-rows x 128 keys = 512 int4, 2/thread
    const int vr = tid >> 3, vcc = (tid & 7) * 2;
    const int voff = vr * VROW + vcc * 8;
    const f16* vrow = vb + (size_t)vr * NPIX;

    const h2 one2 = {(__fp16)1.0f, (__fp16)1.0f};

    // Q B-frags (B[k=d][n=q]): two 16-q subtiles
    f16x8 qB[2];
#pragma unroll
    for (int h = 0; h < 2; ++h)
        qB[h] = *(const f16x8*)(qh + ((size_t)bh * NPIX + qbase + h * 16 + l16) * 32 + quad * 8);

    floatx4 oacc[2][2];
#pragma unroll
    for (int h = 0; h < 2; ++h)
#pragma unroll
        for (int dh = 0; dh < 2; ++dh) oacc[h][dh] = floatx4{0.f, 0.f, 0.f, 0.f};
    float lsum[2] = {0.f, 0.f};

    // prologue: V tile 0 -> vlds[0]; K tile 0 frags -> kfA
    f16x8 kfA[8], kfB[8];
    {
        const int4* vs = (const int4*)vrow;
        int4 a = vs[vcc], b2 = vs[vcc + 1];
        *(int4*)&vlds[0][voff]     = a;
        *(int4*)&vlds[0][voff + 8] = b2;
    }
#pragma unroll
    for (int t = 0; t < 8; ++t)
        kfA[t] = *(const f16x8*)(kp + (size_t)(t * 16) * 32);
    __syncthreads();

    for (int it = 0; it < NT / 2; ++it) {
        const int t0 = it * 2;
        ATTN_STEP(0, kfA, kfB, t0 + 1);   // tile t0   (even -> buf 0)
        ATTN_STEP(1, kfB, kfA, t0 + 2);   // tile t0+1 (odd  -> buf 1)
    }

    // epilogue: reduce lsum across quads (q lives in l16), divide, store f16
#pragma unroll
    for (int h = 0; h < 2; ++h) {
        float l = lsum[h];
        l += __shfl_xor(l, 16);
        l += __shfl_xor(l, 32);
        const float inv = 1.0f / l;            // valid per q = l16
#pragma unroll
        for (int r = 0; r < 4; ++r) {
            const float invr = __shfl(inv, quad * 4 + r);   // inv for q-row quad*4+r
            const int q = qbase + h * 16 + quad * 4 + r;
            f16* ob = att + ((size_t)bh * NPIX + q) * 32;
            ob[l16]      = (f16)(oacc[h][0][r] * invr);
            ob[16 + l16] = (f16)(oacc[h][1][r] * invr);
        }
    }
}

// ---------------------------------------------------------------------------
// Kernel 3: output projection as fp16 MFMA GEMM.  (round-0 form, known-good)
// C[o][p] = Wp[o][c] * att^T[c][p] + bias; att[bh][p][32] IS the natural
// B-fragment layout (16B contiguous per lane). Stores coalesced fp32.
// grid (64 p-tiles, 4 b), block 256 (4 waves).
// ---------------------------------------------------------------------------
__global__ __launch_bounds__(256) void proj_mfma(
    const f16* __restrict__ att, const float* __restrict__ wp,
    const float* __restrict__ bp, float* __restrict__ out)
{
    __shared__ f16 wplds[128 * 136];   // [o][c] padded, 34.8 KB
    __shared__ float bplds[128];
    const int tid  = threadIdx.x;
    const int wave = tid >> 6;
    const int lane = tid & 63;
    const int quad = lane >> 4;
    const int l16  = lane & 15;
    const int pbase = blockIdx.x * 64;
    const int b     = blockIdx.y;

    if (tid < 128) bplds[tid] = bp[tid];
#pragma unroll
    for (int i = 0; i < 16; ++i) {
        int idx = i * 256 + tid;               // 4096 float4 = 128*128 floats
        int o = idx >> 5, ch = idx & 31;
        float4 wv = *(const float4*)(wp + (size_t)o * 128 + ch * 4);
        f16x4 h; h[0] = (f16)wv.x; h[1] = (f16)wv.y; h[2] = (f16)wv.z; h[3] = (f16)wv.w;
        *(f16x4*)&wplds[o * 136 + ch * 4] = h;
    }
    __syncthreads();

    const f16* ab = att + (size_t)b * 4 * NPIX * 32;
    const int p_col = pbase + wave * 16 + l16;
    f16x8 bf[4];
#pragma unroll
    for (int kc = 0; kc < 4; ++kc)
        bf[kc] = *(const f16x8*)(ab + ((size_t)kc * NPIX + p_col) * 32 + quad * 8);

    floatx4 acc[8];
#pragma unroll
    for (int m = 0; m < 8; ++m) acc[m] = floatx4{0.f, 0.f, 0.f, 0.f};
#pragma unroll
    for (int m = 0; m < 8; ++m)
#pragma unroll
        for (int kc = 0; kc < 4; ++kc) {
            f16x8 af = *(const f16x8*)&wplds[(m * 16 + l16) * 136 + kc * 32 + quad * 8];
            acc[m] = __builtin_amdgcn_mfma_f32_16x16x32_f16(af, bf[kc], acc[m], 0, 0, 0);
        }

#pragma unroll
    for (int m = 0; m < 8; ++m)
#pragma unroll
        for (int r = 0; r < 4; ++r) {
            const int o = m * 16 + quad * 4 + r;
            out[((size_t)b * 128 + o) * NPIX + p_col] = acc[m][r] + bplds[o];
        }
}

// ---------------------------------------------------------------------------
extern "C" void kernel_launch(void* const* d_in, const int* in_sizes, int n_in,
                              void* d_out, int out_size, void* d_ws, size_t ws_size,
                              hipStream_t stream)
{
    const float* x      = (const float*)d_in[0];
    const float* w_qkv  = (const float*)d_in[1];
    const float* w_proj = (const float*)d_in[2];
    const float* b_proj = (const float*)d_in[3];
    float* out = (float*)d_out;

    char* ws = (char*)d_ws;
    f16* qh  = (f16*)(ws);                // 4 MB [bh][p][32], pre-scaled
    f16* kh  = (f16*)(ws + (4u << 20));   // 4 MB [bh][p][32]
    f16* vth = (f16*)(ws + (8u << 20));   // 4 MB [bh][d][p]
    f16* att = (f16*)(ws + (12u << 20));  // 4 MB [bh][p][32]

    qkv_mfma<<<dim3(64, 6, 4), 256, 0, stream>>>(x, w_qkv, qh, kh, vth);
    attn_kernel<<<dim3(32, 16, 1), 256, 0, stream>>>(qh, kh, vth, att);
    proj_mfma<<<dim3(64, 4, 1), 256, 0, stream>>>(att, w_proj, b_proj, out);
}